// Round 2
// baseline (162.146 us; speedup 1.0000x reference)
//
#include <hip/hip_runtime.h>

// Unbiased EWMA normalization, s:(16,2000,257,2) fp32, sequential over T.
// Round 2: hoist all t-only scalars (r=1/(1-beta^t), w, 1-w) into an LDS
// table built once per block (double-precision binary exponentiation ->
// exact). The per-step recurrence chains shrink to:
//   v1-chain: 1 fma          (~6 cyc dependent latency)
//   S-chain : fma + max      (~12 cyc)
// rsq / y / store are leaves. 16-step register prefetch ring unchanged.
// Grid: 129 x 7 chunk-blocks (warm-up 512 steps, beta^512 ~ 5.9e-3; round-1
// measured absmax 0.031 vs 0.1 threshold).

#define NN 16
#define TT 2000
#define FCC 514               // F*C
#define SERIES (NN * FCC)     // 8224
#define EPSF 1e-5f
#define NCHUNK 7
#define CLEN 286              // ceil(2000/7)
#define WARM 512
#define PF 16
#define MAXL 800              // max steps per chunk = 286+512=798

__global__ __launch_bounds__(64)
void ewma_kernel(const float* __restrict__ s, float* __restrict__ out) {
    __shared__ float4 tab[MAXL];   // (r, w, 1-w, 0) per step; broadcast reads

    const int chunk = blockIdx.y;
    const int t_out = chunk * CLEN;
    int t_end = t_out + CLEN; if (t_end > TT) t_end = TT;
    int t0 = t_out - WARM;     if (t0 < 0) t0 = 0;
    const int L = t_end - t0;

    // ---- build t-table cooperatively (once per block) ----
    {
        // lane j starts at exponent e = t0+1+lane (beta_t after update is
        // beta^(t+1) for x-index t), then advances by beta^64 per iteration.
        double bd = 0.99, acc = 1.0;
        int e = t0 + 1 + (int)threadIdx.x;
        while (e) { if (e & 1) acc *= bd; bd *= bd; e >>= 1; }
        double b64 = 0.99;
        for (int i = 0; i < 6; ++i) b64 *= b64;       // beta^64
        for (int j = (int)threadIdx.x; j < L; j += 64) {
            const float om = (float)(1.0 - acc);      // 1 - beta^t, near-exact
            const float r  = __builtin_amdgcn_rcpf(om);
            const float w  = 0.01f * r;               // (1-beta)/(1-beta^t)
            tab[j] = make_float4(r, w, 1.0f - w, 0.0f);
            acc *= b64;
        }
    }
    __syncthreads();

    const int tid = blockIdx.x * 64 + (int)threadIdx.x;
    if (tid >= SERIES) return;                        // after the only barrier

    const int n  = tid / FCC;
    const int fc = tid - n * FCC;
    const size_t base = (size_t)n * TT * FCC + (size_t)fc + (size_t)t0 * FCC;
    const float* p  = s   + base;
    float*       po = out + base;

    float v1 = 0.0f, v2p = 0.0f, S = 0.0f;

    float buf[PF];
    #pragma unroll
    for (int i = 0; i < PF; ++i) buf[i] = p[i * FCC];

    int t = t0, j = 0;
    while (t + PF <= t_end) {
        // prefetch next group (in-bounds dummy re-read when no next group)
        const float* pf_ptr = (t + 2 * PF <= t_end) ? (p + PF * FCC) : p;
        float nbuf[PF];
        #pragma unroll
        for (int i = 0; i < PF; ++i) nbuf[i] = pf_ptr[i * FCC];

        const bool full_out = (t >= t_out);           // wave-uniform
        #pragma unroll
        for (int i = 0; i < PF; ++i) {
            const float4 tw = tab[j + i];             // ds_read_b128 broadcast
            const float x  = buf[i];
            v1 = fmaf(0.99f, v1, 0.01f * x);          // v1-chain: 1 fma
            const float v2 = v1 * tw.x;
            const float d  = x - v2;
            const float pr = d * (x - v2p);
            S = fmaxf(fmaf(tw.z, S, tw.y * pr), 0.0f); // S-chain: fma+max
            const float y = d * __builtin_amdgcn_rsqf(S + EPSF); // leaf
            v2p = v2;
            if (full_out || (t + i >= t_out)) po[i * FCC] = y;
        }

        #pragma unroll
        for (int i = 0; i < PF; ++i) buf[i] = nbuf[i];
        p  += PF * FCC;
        po += PF * FCC;
        t  += PF;
        j  += PF;
    }
    for (; t < t_end; ++t, ++j) {                     // tail (< PF steps)
        const float4 tw = tab[j];
        const float x  = *p;
        v1 = fmaf(0.99f, v1, 0.01f * x);
        const float v2 = v1 * tw.x;
        const float d  = x - v2;
        const float pr = d * (x - v2p);
        S = fmaxf(fmaf(tw.z, S, tw.y * pr), 0.0f);
        const float y = d * __builtin_amdgcn_rsqf(S + EPSF);
        v2p = v2;
        if (t >= t_out) *po = y;
        p  += FCC;
        po += FCC;
    }
}

extern "C" void kernel_launch(void* const* d_in, const int* in_sizes, int n_in,
                              void* d_out, int out_size, void* d_ws, size_t ws_size,
                              hipStream_t stream) {
    const float* s = (const float*)d_in[0];
    float* out = (float*)d_out;
    dim3 grid((SERIES + 63) / 64, NCHUNK);   // 129 x 7 blocks of 64
    ewma_kernel<<<grid, dim3(64), 0, stream>>>(s, out);
}